// Round 1
// baseline (1947.136 us; speedup 1.0000x reference)
//
#include <hip/hip_runtime.h>

// GraphNet interaction network, fp32 baseline.
// Sizes fixed by the reference:
#define BB   32
#define NN   188
#define PP   16
#define NE   (NN*(NN-1))        // 35156 edges per batch
#define HID  128
#define HH2  64
#define DE   5
#define DO   6
#define NT   5
#define ROWS_E (BB*NE)          // 1,124,992 edge rows total (divisible by 32)
#define ROWS_O (BB*NN)          // 6016 object rows (divisible by 32)
#define RT   32                 // rows per tile
#define KO   (PP+DE)            // 21 = object-MLP input width

// ---------------------------------------------------------------------------
// Edge MLP: e_in(32) -> 128 relu -> 64 relu -> 5 relu, scatter-add to Ebar.
// 512 threads, 32 rows/block. Static LDS 62.4 KB -> 2 blocks/CU.
// ---------------------------------------------------------------------------
__global__ __launch_bounds__(512)
void edge_mlp_kernel(const float* __restrict__ x,
                     const float* __restrict__ w1, const float* __restrict__ b1,
                     const float* __restrict__ w2, const float* __restrict__ b2,
                     const float* __restrict__ w3, const float* __restrict__ b3,
                     float* __restrict__ ebar)
{
    __shared__ float sW[HID*HH2];        // 8192 floats: holds W1 then W2
    __shared__ float sB1[HID];
    __shared__ float sB2[HH2];
    __shared__ float sEin[RT*32];        // 1024
    __shared__ float sH1[RT*HID];        // 4096
    __shared__ float sH2t[HH2*(RT+1)];   // 2112, [j][r] padded to 33
    const int tid = threadIdx.x;
    const int rbase = blockIdx.x * RT;

    // stage W1 + biases + gathered edge inputs
    for (int i = tid; i < 32*HID; i += 512) sW[i] = w1[i];
    if (tid < HID) sB1[tid] = b1[tid];
    else if (tid < HID+HH2) sB2[tid-HID] = b2[tid-HID];
    for (int i = tid; i < RT*32; i += 512) {
        int r = i >> 5, k = i & 31;
        int gr = rbase + r;
        int b  = gr / NE;
        int e  = gr - b*NE;
        int recv = e / (NN-1);
        int rem  = e - recv*(NN-1);
        int send = rem + (rem >= recv ? 1 : 0);
        int node = (k < PP) ? recv : send;
        sEin[i] = x[(b*NN + node)*PP + (k & (PP-1))];
    }
    __syncthreads();

    // ---- layer 1: 32 -> 128 ----
    {
        const int j = tid & (HID-1);
        const int g = tid >> 7;                 // 4 groups x 8 rows
        float w[32];
        #pragma unroll
        for (int k = 0; k < 32; ++k) w[k] = sW[k*HID + j];   // lanes stride-1: no conflict
        const float bj = sB1[j];
        #pragma unroll
        for (int rr = 0; rr < 8; ++rr) {
            const int r = g*8 + rr;
            const float* e = &sEin[r*32];       // wave-uniform -> LDS broadcast
            float a0=0.f,a1=0.f,a2=0.f,a3=0.f;
            #pragma unroll
            for (int k = 0; k < 32; k += 4) {
                a0 += w[k+0]*e[k+0];
                a1 += w[k+1]*e[k+1];
                a2 += w[k+2]*e[k+2];
                a3 += w[k+3]*e[k+3];
            }
            float v = (a0+a1)+(a2+a3)+bj;
            sH1[r*HID + j] = v > 0.f ? v : 0.f;
        }
    }
    __syncthreads();
    // stage W2 over the W1 region
    for (int i = tid; i < HID*HH2; i += 512) sW[i] = w2[i];
    __syncthreads();

    // ---- layer 2: 128 -> 64 ----
    {
        const int j = tid & (HH2-1);
        const int g = tid >> 6;                 // 8 groups x 4 rows
        float acc[4];
        #pragma unroll
        for (int rr = 0; rr < 4; ++rr) acc[rr] = sB2[j];
        #pragma unroll
        for (int kc = 0; kc < HID; kc += 32) {
            float w[32];
            #pragma unroll
            for (int kk = 0; kk < 32; ++kk) w[kk] = sW[(kc+kk)*HH2 + j];
            #pragma unroll
            for (int rr = 0; rr < 4; ++rr) {
                const float* h = &sH1[(g*4+rr)*HID + kc];   // broadcast
                float a0=0.f,a1=0.f,a2=0.f,a3=0.f;
                #pragma unroll
                for (int kk = 0; kk < 32; kk += 4) {
                    a0 += w[kk+0]*h[kk+0];
                    a1 += w[kk+1]*h[kk+1];
                    a2 += w[kk+2]*h[kk+2];
                    a3 += w[kk+3]*h[kk+3];
                }
                acc[rr] += (a0+a1)+(a2+a3);
            }
        }
        #pragma unroll
        for (int rr = 0; rr < 4; ++rr) {
            float v = acc[rr];
            sH2t[j*(RT+1) + (g*4+rr)] = v > 0.f ? v : 0.f;  // transposed: layer-3 reads stride-1
        }
    }
    __syncthreads();

    // ---- layer 3: 64 -> 5 + relu + atomic scatter to receiver ----
    if (tid < RT*DE) {                          // 160 threads
        const int r = tid & (RT-1);
        const int c = tid >> 5;                 // 0..4
        float a0=0.f,a1=0.f,a2=0.f,a3=0.f;
        #pragma unroll
        for (int k = 0; k < HH2; k += 4) {
            a0 += sH2t[(k+0)*(RT+1)+r]*w3[(k+0)*DE+c];
            a1 += sH2t[(k+1)*(RT+1)+r]*w3[(k+1)*DE+c];
            a2 += sH2t[(k+2)*(RT+1)+r]*w3[(k+2)*DE+c];
            a3 += sH2t[(k+3)*(RT+1)+r]*w3[(k+3)*DE+c];
        }
        float v = (a0+a1)+(a2+a3) + b3[c];
        v = v > 0.f ? v : 0.f;
        int gr = rbase + r;
        int b  = gr / NE;
        int e  = gr - b*NE;
        int recv = e / (NN-1);
        atomicAdd(&ebar[(b*NN + recv)*DE + c], v);
    }
}

// ---------------------------------------------------------------------------
// Object MLP: [x(16) | Ebar(5)] -> 128 relu -> 64 relu -> 6 relu, write O
// in fc1 flattened layout o[b*1128 + node*6 + c].
// ---------------------------------------------------------------------------
__global__ __launch_bounds__(512)
void obj_mlp_kernel(const float* __restrict__ x, const float* __restrict__ ebar,
                    const float* __restrict__ w1, const float* __restrict__ b1,
                    const float* __restrict__ w2, const float* __restrict__ b2,
                    const float* __restrict__ w3, const float* __restrict__ b3,
                    float* __restrict__ o_out)
{
    __shared__ float sW[HID*HH2];
    __shared__ float sB1[HID];
    __shared__ float sB2[HH2];
    __shared__ float sCin[RT*KO];        // 672
    __shared__ float sH1[RT*HID];
    __shared__ float sH2t[HH2*(RT+1)];
    const int tid = threadIdx.x;
    const int rbase = blockIdx.x * RT;

    for (int i = tid; i < KO*HID; i += 512) sW[i] = w1[i];
    if (tid < HID) sB1[tid] = b1[tid];
    else if (tid < HID+HH2) sB2[tid-HID] = b2[tid-HID];
    for (int i = tid; i < RT*KO; i += 512) {
        int r = i / KO, k = i - r*KO;
        int gr = rbase + r;
        int b = gr / NN;
        int node = gr - b*NN;
        sCin[i] = (k < PP) ? x[(b*NN+node)*PP + k]
                           : ebar[(b*NN+node)*DE + (k-PP)];
    }
    __syncthreads();

    // layer 1: 21 -> 128
    {
        const int j = tid & (HID-1);
        const int g = tid >> 7;
        float w[KO];
        #pragma unroll
        for (int k = 0; k < KO; ++k) w[k] = sW[k*HID + j];
        const float bj = sB1[j];
        #pragma unroll
        for (int rr = 0; rr < 8; ++rr) {
            const int r = g*8 + rr;
            const float* e = &sCin[r*KO];
            float a0=0.f,a1=0.f,a2=0.f;
            #pragma unroll
            for (int k = 0; k < KO; k += 3) {   // 21 = 7*3
                a0 += w[k+0]*e[k+0];
                a1 += w[k+1]*e[k+1];
                a2 += w[k+2]*e[k+2];
            }
            float v = a0+a1+a2+bj;
            sH1[r*HID + j] = v > 0.f ? v : 0.f;
        }
    }
    __syncthreads();
    for (int i = tid; i < HID*HH2; i += 512) sW[i] = w2[i];
    __syncthreads();

    // layer 2: 128 -> 64
    {
        const int j = tid & (HH2-1);
        const int g = tid >> 6;
        float acc[4];
        #pragma unroll
        for (int rr = 0; rr < 4; ++rr) acc[rr] = sB2[j];
        #pragma unroll
        for (int kc = 0; kc < HID; kc += 32) {
            float w[32];
            #pragma unroll
            for (int kk = 0; kk < 32; ++kk) w[kk] = sW[(kc+kk)*HH2 + j];
            #pragma unroll
            for (int rr = 0; rr < 4; ++rr) {
                const float* h = &sH1[(g*4+rr)*HID + kc];
                float a0=0.f,a1=0.f,a2=0.f,a3=0.f;
                #pragma unroll
                for (int kk = 0; kk < 32; kk += 4) {
                    a0 += w[kk+0]*h[kk+0];
                    a1 += w[kk+1]*h[kk+1];
                    a2 += w[kk+2]*h[kk+2];
                    a3 += w[kk+3]*h[kk+3];
                }
                acc[rr] += (a0+a1)+(a2+a3);
            }
        }
        #pragma unroll
        for (int rr = 0; rr < 4; ++rr) {
            float v = acc[rr];
            sH2t[j*(RT+1) + (g*4+rr)] = v > 0.f ? v : 0.f;
        }
    }
    __syncthreads();

    // layer 3: 64 -> 6 + relu
    if (tid < RT*DO) {                          // 192 threads
        const int r = tid & (RT-1);
        const int c = tid >> 5;                 // 0..5
        float a0=0.f,a1=0.f,a2=0.f,a3=0.f;
        #pragma unroll
        for (int k = 0; k < HH2; k += 4) {
            a0 += sH2t[(k+0)*(RT+1)+r]*w3[(k+0)*DO+c];
            a1 += sH2t[(k+1)*(RT+1)+r]*w3[(k+1)*DO+c];
            a2 += sH2t[(k+2)*(RT+1)+r]*w3[(k+2)*DO+c];
            a3 += sH2t[(k+3)*(RT+1)+r]*w3[(k+3)*DO+c];
        }
        float v = (a0+a1)+(a2+a3) + b3[c];
        v = v > 0.f ? v : 0.f;
        int gr = rbase + r;
        int b = gr / NN;
        int node = gr - b*NN;
        o_out[b*(NN*DO) + node*DO + c] = v;
    }
}

// ---------------------------------------------------------------------------
// Classifier: 1128 -> 128 relu -> 64 relu -> 5. One block per batch row.
// ---------------------------------------------------------------------------
__global__ __launch_bounds__(256)
void fc_kernel(const float* __restrict__ o_in,
               const float* __restrict__ w1, const float* __restrict__ b1,
               const float* __restrict__ w2, const float* __restrict__ b2,
               const float* __restrict__ w3, const float* __restrict__ b3,
               float* __restrict__ out)
{
    __shared__ float s_in[NN*DO];    // 1128
    __shared__ float s_p[256];
    __shared__ float s_h1[HID];
    __shared__ float s_h2[HH2];
    const int b = blockIdx.x, tid = threadIdx.x;

    for (int i = tid; i < NN*DO; i += 256) s_in[i] = o_in[b*(NN*DO) + i];
    __syncthreads();

    // L1: 1128 -> 128 (two k-halves of 564 per output)
    {
        const int j = tid & (HID-1);
        const int h = tid >> 7;
        float acc = 0.f;
        const int k0 = h*564;
        for (int k = k0; k < k0+564; ++k)
            acc += s_in[k] * w1[k*HID + j];     // coalesced global, L2-hot
        s_p[tid] = acc;
    }
    __syncthreads();
    if (tid < HID) {
        float v = s_p[tid] + s_p[tid+HID] + b1[tid];
        s_h1[tid] = v > 0.f ? v : 0.f;
    }
    __syncthreads();

    // L2: 128 -> 64 (four k-quarters of 32)
    {
        const int j = tid & (HH2-1);
        const int q = tid >> 6;
        float acc = 0.f;
        #pragma unroll
        for (int kk = 0; kk < 32; ++kk) {
            int k = q*32 + kk;
            acc += s_h1[k] * w2[k*HH2 + j];
        }
        s_p[tid] = acc;
    }
    __syncthreads();
    if (tid < HH2) {
        float v = s_p[tid] + s_p[tid+64] + s_p[tid+128] + s_p[tid+192] + b2[tid];
        s_h2[tid] = v > 0.f ? v : 0.f;
    }
    __syncthreads();

    // L3: 64 -> 5 (no relu)
    if (tid < NT) {
        float acc = b3[tid];
        #pragma unroll
        for (int k = 0; k < HH2; ++k)
            acc += s_h2[k] * w3[k*NT + tid];
        out[b*NT + tid] = acc;
    }
}

extern "C" void kernel_launch(void* const* d_in, const int* in_sizes, int n_in,
                              void* d_out, int out_size, void* d_ws, size_t ws_size,
                              hipStream_t stream) {
    (void)in_sizes; (void)n_in; (void)out_size; (void)ws_size;
    const float* x     = (const float*)d_in[0];
    const float* fr1_w = (const float*)d_in[1];
    const float* fr1_b = (const float*)d_in[2];
    const float* fr2_w = (const float*)d_in[3];
    const float* fr2_b = (const float*)d_in[4];
    const float* fr3_w = (const float*)d_in[5];
    const float* fr3_b = (const float*)d_in[6];
    const float* fo1_w = (const float*)d_in[7];
    const float* fo1_b = (const float*)d_in[8];
    const float* fo2_w = (const float*)d_in[9];
    const float* fo2_b = (const float*)d_in[10];
    const float* fo3_w = (const float*)d_in[11];
    const float* fo3_b = (const float*)d_in[12];
    const float* fc1_w = (const float*)d_in[13];
    const float* fc1_b = (const float*)d_in[14];
    const float* fc2_w = (const float*)d_in[15];
    const float* fc2_b = (const float*)d_in[16];
    const float* fc3_w = (const float*)d_in[17];
    const float* fc3_b = (const float*)d_in[18];

    float* ws   = (float*)d_ws;
    float* ebar = ws;                       // BB*NN*DE = 30080 floats
    float* o_ws = ws + BB*NN*DE;            // BB*NN*DO = 36096 floats

    // Ebar must start at zero (workspace is poisoned before every launch).
    hipMemsetAsync(ebar, 0, (size_t)(BB*NN*DE)*sizeof(float), stream);

    edge_mlp_kernel<<<ROWS_E/RT, 512, 0, stream>>>(
        x, fr1_w, fr1_b, fr2_w, fr2_b, fr3_w, fr3_b, ebar);
    obj_mlp_kernel<<<ROWS_O/RT, 512, 0, stream>>>(
        x, ebar, fo1_w, fo1_b, fo2_w, fo2_b, fo3_w, fo3_b, o_ws);
    fc_kernel<<<BB, 256, 0, stream>>>(
        o_ws, fc1_w, fc1_b, fc2_w, fc2_b, fc3_w, fc3_b, (float*)d_out);
}

// Round 2
// 202.620 us; speedup vs baseline: 9.6098x; 9.6098x over previous
//
#include <hip/hip_runtime.h>

// GraphNet interaction network. Edge MLP via bf16 MFMA (fp32 accum),
// one block per (batch, receiver) -> scatter becomes block-local reduce.
#define BB   32
#define NN   188
#define PP   16
#define HID  128
#define HH2  64
#define DE   5
#define DO   6
#define NT   5
#define ROWS_O (BB*NN)          // 6016 object rows
#define RT   32                 // rows per tile (obj kernel)
#define KO   (PP+DE)            // 21

typedef __attribute__((ext_vector_type(8))) short short8;   // 8 bf16 = 4 VGPRs
typedef __attribute__((ext_vector_type(4))) float float4_;

__device__ __forceinline__ short f2bf(float v) {
    union { float f; unsigned u; } a; a.f = v;
    unsigned r = a.u + 0x7fff + ((a.u >> 16) & 1);   // round-to-nearest-even
    return (short)(r >> 16);
}

// workspace layout (shorts/floats)
#define XB_OFF    0                       // bf16 [32][188][24]   (pad 16->24)
#define XB_ELTS   (BB*NN*24)
#define W1T_OFF   (XB_OFF + XB_ELTS)      // bf16 [128 n][40 k]   (k pad 32->40)
#define W1T_ELTS  (HID*40)
#define W2T_OFF   (W1T_OFF + W1T_ELTS)    // bf16 [64 n][136 k]   (k pad 128->136)
#define W2T_ELTS  (HH2*136)
#define W3PT_OFF  (W2T_OFF + W2T_ELTS)    // bf16 [16 n][72 k]    (n pad 5->16 zeros, k pad 64->72)
#define W3PT_ELTS (16*72)
#define SHORT_TOTAL (W3PT_OFF + W3PT_ELTS)

// ---------------------------------------------------------------------------
// Prep: fp32 -> bf16 conversions + weight transposes into d_ws.
// ---------------------------------------------------------------------------
__global__ void prep_kernel(const float* __restrict__ x,
                            const float* __restrict__ w1,
                            const float* __restrict__ w2,
                            const float* __restrict__ w3,
                            short* __restrict__ ws)
{
    short* xb   = ws + XB_OFF;
    short* w1t  = ws + W1T_OFF;
    short* w2t  = ws + W2T_OFF;
    short* w3pt = ws + W3PT_OFF;
    const int i = blockIdx.x * blockDim.x + threadIdx.x;
    const int stride = gridDim.x * blockDim.x;
    for (int idx = i; idx < BB*NN*PP; idx += stride) {       // x -> xb
        int row = idx >> 4, k = idx & 15;
        xb[row*24 + k] = f2bf(x[idx]);
    }
    for (int idx = i; idx < 32*HID; idx += stride) {         // w1 [k=32][n=128] -> [n][k]
        int k = idx >> 7, n = idx & 127;
        w1t[n*40 + k] = f2bf(w1[idx]);
    }
    for (int idx = i; idx < HID*HH2; idx += stride) {        // w2 [k=128][n=64] -> [n][k]
        int k = idx >> 6, n = idx & 63;
        w2t[n*136 + k] = f2bf(w2[idx]);
    }
    for (int idx = i; idx < 16*64; idx += stride) {          // w3 [k=64][n=5] -> [n 16][k], zero pad
        int n = idx >> 6, k = idx & 63;
        w3pt[n*72 + k] = (n < DE) ? f2bf(w3[k*DE + n]) : (short)0;
    }
}

// ---------------------------------------------------------------------------
// Edge MLP: 32 -> 128 relu -> 64 relu -> 5 relu, summed over the 187 edges of
// one (batch, receiver). bf16 MFMA 16x16x32, fp32 accumulate.
// 256 threads = 4 waves; each wave handles 3 row-tiles of 16 edges (192 >= 187).
// ---------------------------------------------------------------------------
__global__ __launch_bounds__(256)
void edge_mfma_kernel(const short* __restrict__ ws_s,
                      const float* __restrict__ b1,
                      const float* __restrict__ b2,
                      const float* __restrict__ b3,
                      float* __restrict__ ebar)
{
    const short* xb   = ws_s + XB_OFF;
    const short* w1t  = ws_s + W1T_OFF;
    const short* w2t  = ws_s + W2T_OFF;
    const short* w3pt = ws_s + W3PT_OFF;

    __shared__ __align__(16) short h1s[4][16*136];   // per-wave, 17408 B total
    __shared__ __align__(16) short h2s[4][16*72];    // per-wave,  9216 B total
    __shared__ float red[4][DE];

    const int bi   = blockIdx.x;           // b*188 + recv
    const int b    = bi / NN;
    const int recv = bi - b*NN;
    const int tid  = threadIdx.x;
    const int wave = tid >> 6;
    const int lane = tid & 63;
    const int n16  = lane & 15;            // col (B/C) or row (A)
    const int q    = lane >> 4;            // k-chunk (A/B) or row-group (C)

    // hoisted B fragments (global, L2-hot, reused for 3 row-tiles)
    short8 B1[8];
    #pragma unroll
    for (int t = 0; t < 8; ++t)
        B1[t] = *(const short8*)(w1t + (t*16 + n16)*40 + q*8);
    short8 B2[16];
    #pragma unroll
    for (int t = 0; t < 4; ++t)
        #pragma unroll
        for (int s = 0; s < 4; ++s)
            B2[t*4+s] = *(const short8*)(w2t + (t*16 + n16)*136 + s*32 + q*8);
    short8 B3[2];
    #pragma unroll
    for (int s = 0; s < 2; ++s)
        B3[s] = *(const short8*)(w3pt + n16*72 + s*32 + q*8);

    float bias1[8];
    #pragma unroll
    for (int t = 0; t < 8; ++t) bias1[t] = b1[t*16 + n16];
    float bias2[4];
    #pragma unroll
    for (int t = 0; t < 4; ++t) bias2[t] = b2[t*16 + n16];
    const float bias3 = (n16 < DE) ? b3[n16] : 0.f;

    const short* xrow = xb + b*(NN*24);
    short* h1 = &h1s[wave][0];
    short* h2 = &h2s[wave][0];

    float acc[4] = {0.f, 0.f, 0.f, 0.f};

    #pragma unroll
    for (int ti = 0; ti < 3; ++ti) {
        const int rowbase = (wave*3 + ti) * 16;
        // ---- A frag for layer 1: [x[recv] | x[send_r]] ----
        const int r = rowbase + n16;                   // edge idx 0..191
        int send = r + (r >= recv ? 1 : 0);
        if (send > NN-1) send = NN-1;                  // clamp padding rows
        const int node = (q < 2) ? recv : send;
        const int koff = (q & 1) * 8;
        short8 A1 = *(const short8*)(xrow + node*24 + koff);

        // ---- layer 1: 8 N-tiles of 16, K=32 ----
        float4_ C1[8];
        #pragma unroll
        for (int t = 0; t < 8; ++t) {
            C1[t] = (float4_){bias1[t], bias1[t], bias1[t], bias1[t]};
            C1[t] = __builtin_amdgcn_mfma_f32_16x16x32_bf16(A1, B1[t], C1[t], 0, 0, 0);
        }
        // relu + bf16 -> LDS in A-layout [row][k]
        #pragma unroll
        for (int t = 0; t < 8; ++t)
            #pragma unroll
            for (int rg = 0; rg < 4; ++rg) {
                float v = C1[t][rg];
                v = v > 0.f ? v : 0.f;
                h1[(q*4+rg)*136 + t*16 + n16] = f2bf(v);
            }
        __syncthreads();

        // ---- layer 2: 4 N-tiles, K=128 in 4 steps ----
        short8 A2[4];
        #pragma unroll
        for (int s = 0; s < 4; ++s)
            A2[s] = *(const short8*)(h1 + n16*136 + s*32 + q*8);
        float4_ C2[4];
        #pragma unroll
        for (int t = 0; t < 4; ++t) {
            C2[t] = (float4_){bias2[t], bias2[t], bias2[t], bias2[t]};
            #pragma unroll
            for (int s = 0; s < 4; ++s)
                C2[t] = __builtin_amdgcn_mfma_f32_16x16x32_bf16(A2[s], B2[t*4+s], C2[t], 0, 0, 0);
        }
        #pragma unroll
        for (int t = 0; t < 4; ++t)
            #pragma unroll
            for (int rg = 0; rg < 4; ++rg) {
                float v = C2[t][rg];
                v = v > 0.f ? v : 0.f;
                h2[(q*4+rg)*72 + t*16 + n16] = f2bf(v);
            }
        __syncthreads();

        // ---- layer 3: N=16 (5 used), K=64 in 2 steps ----
        float4_ C3 = (float4_){bias3, bias3, bias3, bias3};
        #pragma unroll
        for (int s = 0; s < 2; ++s) {
            short8 A3 = *(const short8*)(h2 + n16*72 + s*32 + q*8);
            C3 = __builtin_amdgcn_mfma_f32_16x16x32_bf16(A3, B3[s], C3, 0, 0, 0);
        }
        #pragma unroll
        for (int rg = 0; rg < 4; ++rg) {
            const int rowid = rowbase + q*4 + rg;
            float e = C3[rg];
            e = e > 0.f ? e : 0.f;
            acc[rg] += (rowid < NN-1) ? e : 0.f;       // mask padding rows
        }
    }

    // reduce: over regs, then over q-groups (same col n16)
    float s = (acc[0] + acc[1]) + (acc[2] + acc[3]);
    s += __shfl_xor(s, 16, 64);
    s += __shfl_xor(s, 32, 64);
    if (lane < DE) red[wave][lane] = s;                // lanes 0..4: q=0, col=lane
    __syncthreads();
    if (wave == 0 && lane < DE) {
        float tot = red[0][lane] + red[1][lane] + red[2][lane] + red[3][lane];
        ebar[bi*DE + lane] = tot;                      // [b][recv][5], plain store
    }
}

// ---------------------------------------------------------------------------
// Object MLP (unchanged fp32 path): [x(16)|Ebar(5)] -> 128 -> 64 -> 6 relu
// ---------------------------------------------------------------------------
__global__ __launch_bounds__(512)
void obj_mlp_kernel(const float* __restrict__ x, const float* __restrict__ ebar,
                    const float* __restrict__ w1, const float* __restrict__ b1,
                    const float* __restrict__ w2, const float* __restrict__ b2,
                    const float* __restrict__ w3, const float* __restrict__ b3,
                    float* __restrict__ o_out)
{
    __shared__ float sW[HID*HH2];
    __shared__ float sB1[HID];
    __shared__ float sB2[HH2];
    __shared__ float sCin[RT*KO];
    __shared__ float sH1[RT*HID];
    __shared__ float sH2t[HH2*(RT+1)];
    const int tid = threadIdx.x;
    const int rbase = blockIdx.x * RT;

    for (int i = tid; i < KO*HID; i += 512) sW[i] = w1[i];
    if (tid < HID) sB1[tid] = b1[tid];
    else if (tid < HID+HH2) sB2[tid-HID] = b2[tid-HID];
    for (int i = tid; i < RT*KO; i += 512) {
        int r = i / KO, k = i - r*KO;
        int gr = rbase + r;
        int b = gr / NN;
        int node = gr - b*NN;
        sCin[i] = (k < PP) ? x[(b*NN+node)*PP + k]
                           : ebar[(b*NN+node)*DE + (k-PP)];
    }
    __syncthreads();

    {
        const int j = tid & (HID-1);
        const int g = tid >> 7;
        float w[KO];
        #pragma unroll
        for (int k = 0; k < KO; ++k) w[k] = sW[k*HID + j];
        const float bj = sB1[j];
        #pragma unroll
        for (int rr = 0; rr < 8; ++rr) {
            const int r = g*8 + rr;
            const float* e = &sCin[r*KO];
            float a0=0.f,a1=0.f,a2=0.f;
            #pragma unroll
            for (int k = 0; k < KO; k += 3) {
                a0 += w[k+0]*e[k+0];
                a1 += w[k+1]*e[k+1];
                a2 += w[k+2]*e[k+2];
            }
            float v = a0+a1+a2+bj;
            sH1[r*HID + j] = v > 0.f ? v : 0.f;
        }
    }
    __syncthreads();
    for (int i = tid; i < HID*HH2; i += 512) sW[i] = w2[i];
    __syncthreads();

    {
        const int j = tid & (HH2-1);
        const int g = tid >> 6;
        float acc[4];
        #pragma unroll
        for (int rr = 0; rr < 4; ++rr) acc[rr] = sB2[j];
        #pragma unroll
        for (int kc = 0; kc < HID; kc += 32) {
            float w[32];
            #pragma unroll
            for (int kk = 0; kk < 32; ++kk) w[kk] = sW[(kc+kk)*HH2 + j];
            #pragma unroll
            for (int rr = 0; rr < 4; ++rr) {
                const float* h = &sH1[(g*4+rr)*HID + kc];
                float a0=0.f,a1=0.f,a2=0.f,a3=0.f;
                #pragma unroll
                for (int kk = 0; kk < 32; kk += 4) {
                    a0 += w[kk+0]*h[kk+0];
                    a1 += w[kk+1]*h[kk+1];
                    a2 += w[kk+2]*h[kk+2];
                    a3 += w[kk+3]*h[kk+3];
                }
                acc[rr] += (a0+a1)+(a2+a3);
            }
        }
        #pragma unroll
        for (int rr = 0; rr < 4; ++rr) {
            float v = acc[rr];
            sH2t[j*(RT+1) + (g*4+rr)] = v > 0.f ? v : 0.f;
        }
    }
    __syncthreads();

    if (tid < RT*DO) {
        const int r = tid & (RT-1);
        const int c = tid >> 5;
        float a0=0.f,a1=0.f,a2=0.f,a3=0.f;
        #pragma unroll
        for (int k = 0; k < HH2; k += 4) {
            a0 += sH2t[(k+0)*(RT+1)+r]*w3[(k+0)*DO+c];
            a1 += sH2t[(k+1)*(RT+1)+r]*w3[(k+1)*DO+c];
            a2 += sH2t[(k+2)*(RT+1)+r]*w3[(k+2)*DO+c];
            a3 += sH2t[(k+3)*(RT+1)+r]*w3[(k+3)*DO+c];
        }
        float v = (a0+a1)+(a2+a3) + b3[c];
        v = v > 0.f ? v : 0.f;
        int gr = rbase + r;
        int b = gr / NN;
        int node = gr - b*NN;
        o_out[b*(NN*DO) + node*DO + c] = v;
    }
}

// ---------------------------------------------------------------------------
// Classifier (unchanged): 1128 -> 128 relu -> 64 relu -> 5
// ---------------------------------------------------------------------------
__global__ __launch_bounds__(256)
void fc_kernel(const float* __restrict__ o_in,
               const float* __restrict__ w1, const float* __restrict__ b1,
               const float* __restrict__ w2, const float* __restrict__ b2,
               const float* __restrict__ w3, const float* __restrict__ b3,
               float* __restrict__ out)
{
    __shared__ float s_in[NN*DO];
    __shared__ float s_p[256];
    __shared__ float s_h1[HID];
    __shared__ float s_h2[HH2];
    const int b = blockIdx.x, tid = threadIdx.x;

    for (int i = tid; i < NN*DO; i += 256) s_in[i] = o_in[b*(NN*DO) + i];
    __syncthreads();

    {
        const int j = tid & (HID-1);
        const int h = tid >> 7;
        float acc = 0.f;
        const int k0 = h*564;
        for (int k = k0; k < k0+564; ++k)
            acc += s_in[k] * w1[k*HID + j];
        s_p[tid] = acc;
    }
    __syncthreads();
    if (tid < HID) {
        float v = s_p[tid] + s_p[tid+HID] + b1[tid];
        s_h1[tid] = v > 0.f ? v : 0.f;
    }
    __syncthreads();

    {
        const int j = tid & (HH2-1);
        const int q = tid >> 6;
        float acc = 0.f;
        #pragma unroll
        for (int kk = 0; kk < 32; ++kk) {
            int k = q*32 + kk;
            acc += s_h1[k] * w2[k*HH2 + j];
        }
        s_p[tid] = acc;
    }
    __syncthreads();
    if (tid < HH2) {
        float v = s_p[tid] + s_p[tid+64] + s_p[tid+128] + s_p[tid+192] + b2[tid];
        s_h2[tid] = v > 0.f ? v : 0.f;
    }
    __syncthreads();

    if (tid < NT) {
        float acc = b3[tid];
        #pragma unroll
        for (int k = 0; k < HH2; ++k)
            acc += s_h2[k] * w3[k*NT + tid];
        out[b*NT + tid] = acc;
    }
}

extern "C" void kernel_launch(void* const* d_in, const int* in_sizes, int n_in,
                              void* d_out, int out_size, void* d_ws, size_t ws_size,
                              hipStream_t stream) {
    (void)in_sizes; (void)n_in; (void)out_size; (void)ws_size;
    const float* x     = (const float*)d_in[0];
    const float* fr1_w = (const float*)d_in[1];
    const float* fr1_b = (const float*)d_in[2];
    const float* fr2_w = (const float*)d_in[3];
    const float* fr2_b = (const float*)d_in[4];
    const float* fr3_w = (const float*)d_in[5];
    const float* fr3_b = (const float*)d_in[6];
    const float* fo1_w = (const float*)d_in[7];
    const float* fo1_b = (const float*)d_in[8];
    const float* fo2_w = (const float*)d_in[9];
    const float* fo2_b = (const float*)d_in[10];
    const float* fo3_w = (const float*)d_in[11];
    const float* fo3_b = (const float*)d_in[12];
    const float* fc1_w = (const float*)d_in[13];
    const float* fc1_b = (const float*)d_in[14];
    const float* fc2_w = (const float*)d_in[15];
    const float* fc2_b = (const float*)d_in[16];
    const float* fc3_w = (const float*)d_in[17];
    const float* fc3_b = (const float*)d_in[18];

    short* ws_s = (short*)d_ws;
    // float region starts after the bf16 region (align to 16B)
    size_t fbase = ((size_t)SHORT_TOTAL*2 + 15) & ~(size_t)15;
    float* ebar = (float*)((char*)d_ws + fbase);            // [32][188][5]
    float* o_ws = ebar + BB*NN*DE;                          // [32][188][6]

    prep_kernel<<<128, 256, 0, stream>>>(x, fr1_w, fr2_w, fr3_w, ws_s);
    edge_mfma_kernel<<<BB*NN, 256, 0, stream>>>(ws_s, fr1_b, fr2_b, fr3_b, ebar);
    obj_mlp_kernel<<<ROWS_O/RT, 512, 0, stream>>>(
        x, ebar, fo1_w, fo1_b, fo2_w, fo2_b, fo3_w, fo3_b, o_ws);
    fc_kernel<<<BB, 256, 0, stream>>>(
        o_ws, fc1_w, fc1_b, fc2_w, fc2_b, fc3_w, fc3_b, (float*)d_out);
}

// Round 3
// 199.663 us; speedup vs baseline: 9.7521x; 1.0148x over previous
//
#include <hip/hip_runtime.h>

// GraphNet interaction network. Edge MLP via bf16 MFMA (fp32 accum),
// one block per (batch, receiver); DPP-packed bf16 LDS stores; no per-tile
// barriers (wave-private LDS buffers).
#define BB   32
#define NN   188
#define PP   16
#define HID  128
#define HH2  64
#define DE   5
#define DO   6
#define NT   5
#define ROWS_O (BB*NN)
#define RT   32
#define KO   (PP+DE)

typedef __attribute__((ext_vector_type(8))) short short8;   // 8 bf16 = 4 VGPRs
typedef __attribute__((ext_vector_type(4))) float float4_;

__device__ __forceinline__ short f2bf(float v) {            // RNE (prep only)
    union { float f; unsigned u; } a; a.f = v;
    unsigned r = a.u + 0x7fff + ((a.u >> 16) & 1);
    return (short)(r >> 16);
}
// relu + round-to-nearest bits: hi16 of result is bf16(max(v,0))
__device__ __forceinline__ unsigned r2u(float v) {
    v = v > 0.f ? v : 0.f;
    return __float_as_uint(v) + 0x8000u;
}
__device__ __forceinline__ unsigned dpp_xor1(unsigned v) {  // lane ^= 1 (quad_perm 1,0,3,2)
    return (unsigned)__builtin_amdgcn_update_dpp(0, (int)v, 0xB1, 0xF, 0xF, true);
}
// pack two pre-rounded uints -> (hi16(hi)<<16)|(hi16(lo))
__device__ __forceinline__ unsigned pack_hi16(unsigned hi, unsigned lo) {
    return __builtin_amdgcn_perm(hi, lo, 0x07060302);
}

// workspace layout (shorts)
#define XB_OFF    0                       // bf16 [32][188][24]
#define XB_ELTS   (BB*NN*24)
#define W1T_OFF   (XB_OFF + XB_ELTS)      // bf16 [128 n][40 k]
#define W1T_ELTS  (HID*40)
#define W2T_OFF   (W1T_OFF + W1T_ELTS)    // bf16 [64 n][136 k]
#define W2T_ELTS  (HH2*136)
#define W3PT_OFF  (W2T_OFF + W2T_ELTS)    // bf16 [16 n][72 k] (n zero-padded)
#define W3PT_ELTS (16*72)
#define SHORT_TOTAL (W3PT_OFF + W3PT_ELTS)

__global__ void prep_kernel(const float* __restrict__ x,
                            const float* __restrict__ w1,
                            const float* __restrict__ w2,
                            const float* __restrict__ w3,
                            short* __restrict__ ws)
{
    short* xb   = ws + XB_OFF;
    short* w1t  = ws + W1T_OFF;
    short* w2t  = ws + W2T_OFF;
    short* w3pt = ws + W3PT_OFF;
    const int i = blockIdx.x * blockDim.x + threadIdx.x;
    const int stride = gridDim.x * blockDim.x;
    for (int idx = i; idx < BB*NN*PP; idx += stride) {
        int row = idx >> 4, k = idx & 15;
        xb[row*24 + k] = f2bf(x[idx]);
    }
    for (int idx = i; idx < 32*HID; idx += stride) {
        int k = idx >> 7, n = idx & 127;
        w1t[n*40 + k] = f2bf(w1[idx]);
    }
    for (int idx = i; idx < HID*HH2; idx += stride) {
        int k = idx >> 6, n = idx & 63;
        w2t[n*136 + k] = f2bf(w2[idx]);
    }
    for (int idx = i; idx < 16*64; idx += stride) {
        int n = idx >> 6, k = idx & 63;
        w3pt[n*72 + k] = (n < DE) ? f2bf(w3[k*DE + n]) : (short)0;
    }
}

// ---------------------------------------------------------------------------
// Edge MLP: 32 -> 128 relu -> 64 relu -> 5 relu, summed over the 187 edges of
// one (batch, receiver). 256 threads = 4 waves; 3 row-tiles of 16 per wave.
// ---------------------------------------------------------------------------
__global__ __launch_bounds__(256)
void edge_mfma_kernel(const short* __restrict__ ws_s,
                      const float* __restrict__ b1,
                      const float* __restrict__ b2,
                      const float* __restrict__ b3,
                      float* __restrict__ ebar)
{
    const short* xb   = ws_s + XB_OFF;
    const short* w1t  = ws_s + W1T_OFF;
    const short* w2t  = ws_s + W2T_OFF;
    const short* w3pt = ws_s + W3PT_OFF;

    __shared__ __align__(16) unsigned h1d[4][16*68];  // [row 16][68 dw] = 136 shorts/row
    __shared__ __align__(16) unsigned h2d[4][16*36];  // [row 16][36 dw] =  72 shorts/row
    __shared__ float red[4][DE];

    const int bi   = blockIdx.x;           // b*188 + recv
    const int b    = bi / NN;
    const int recv = bi - b*NN;
    const int tid  = threadIdx.x;
    const int wave = tid >> 6;
    const int lane = tid & 63;
    const int n16  = lane & 15;
    const int q    = lane >> 4;
    const int p    = n16 & 1;
    const int wcol = p*8 + (n16 >> 1);     // parity-split dword column

    // hoisted B fragments (L2-hot)
    short8 B1[8];
    #pragma unroll
    for (int t = 0; t < 8; ++t)
        B1[t] = *(const short8*)(w1t + (t*16 + n16)*40 + q*8);
    short8 B2[16];
    #pragma unroll
    for (int t = 0; t < 4; ++t)
        #pragma unroll
        for (int s = 0; s < 4; ++s)
            B2[t*4+s] = *(const short8*)(w2t + (t*16 + n16)*136 + s*32 + q*8);
    short8 B3[2];
    #pragma unroll
    for (int s = 0; s < 2; ++s)
        B3[s] = *(const short8*)(w3pt + n16*72 + s*32 + q*8);

    float bias1[8];
    #pragma unroll
    for (int t = 0; t < 8; ++t) bias1[t] = b1[t*16 + n16];
    float bias2[4];
    #pragma unroll
    for (int t = 0; t < 4; ++t) bias2[t] = b2[t*16 + n16];
    const float bias3 = (n16 < DE) ? b3[n16] : 0.f;

    const short* xrow = xb + b*(NN*24);
    unsigned* h1w = &h1d[wave][0];
    unsigned* h2w = &h2d[wave][0];
    const short* h1r = (const short*)h1w;
    const short* h2r = (const short*)h2w;

    float acc[4] = {0.f, 0.f, 0.f, 0.f};

    #pragma unroll
    for (int ti = 0; ti < 3; ++ti) {
        const int rowbase = (wave*3 + ti) * 16;
        // A frag: [x[recv] | x[send_r]]
        const int r = rowbase + n16;
        int send = r + (r >= recv ? 1 : 0);
        if (send > NN-1) send = NN-1;
        const int node = (q < 2) ? recv : send;
        const int koff = (q & 1) * 8;
        short8 A1 = *(const short8*)(xrow + node*24 + koff);

        // ---- layer 1: 8 N-tiles processed as 4 pairs ----
        #pragma unroll
        for (int m = 0; m < 4; ++m) {
            float4_ Ca = (float4_){bias1[2*m],   bias1[2*m],   bias1[2*m],   bias1[2*m]};
            float4_ Cb = (float4_){bias1[2*m+1], bias1[2*m+1], bias1[2*m+1], bias1[2*m+1]};
            Ca = __builtin_amdgcn_mfma_f32_16x16x32_bf16(A1, B1[2*m],   Ca, 0, 0, 0);
            Cb = __builtin_amdgcn_mfma_f32_16x16x32_bf16(A1, B1[2*m+1], Cb, 0, 0, 0);
            #pragma unroll
            for (int rg = 0; rg < 4; ++rg) {
                unsigned u0 = r2u(Ca[rg]);
                unsigned u1 = r2u(Cb[rg]);
                unsigned n0 = dpp_xor1(u0);
                unsigned n1 = dpp_xor1(u1);
                unsigned hi = p ? u1 : n0;
                unsigned lo = p ? n1 : u0;
                h1w[(q*4+rg)*68 + m*16 + wcol] = pack_hi16(hi, lo);
            }
        }

        // ---- layer 2: A frags from wave-private LDS (no barrier needed) ----
        short8 A2[4];
        #pragma unroll
        for (int s = 0; s < 4; ++s)
            A2[s] = *(const short8*)(h1r + n16*136 + s*32 + q*8);
        #pragma unroll
        for (int m = 0; m < 2; ++m) {
            float4_ Ca = (float4_){bias2[2*m],   bias2[2*m],   bias2[2*m],   bias2[2*m]};
            float4_ Cb = (float4_){bias2[2*m+1], bias2[2*m+1], bias2[2*m+1], bias2[2*m+1]};
            #pragma unroll
            for (int s = 0; s < 4; ++s) {
                Ca = __builtin_amdgcn_mfma_f32_16x16x32_bf16(A2[s], B2[(2*m)*4+s],   Ca, 0, 0, 0);
                Cb = __builtin_amdgcn_mfma_f32_16x16x32_bf16(A2[s], B2[(2*m+1)*4+s], Cb, 0, 0, 0);
            }
            #pragma unroll
            for (int rg = 0; rg < 4; ++rg) {
                unsigned u0 = r2u(Ca[rg]);
                unsigned u1 = r2u(Cb[rg]);
                unsigned n0 = dpp_xor1(u0);
                unsigned n1 = dpp_xor1(u1);
                unsigned hi = p ? u1 : n0;
                unsigned lo = p ? n1 : u0;
                h2w[(q*4+rg)*36 + m*16 + wcol] = pack_hi16(hi, lo);
            }
        }

        // ---- layer 3: N=16 (5 used), K=64 ----
        float4_ C3 = (float4_){bias3, bias3, bias3, bias3};
        #pragma unroll
        for (int s = 0; s < 2; ++s) {
            short8 A3 = *(const short8*)(h2r + n16*72 + s*32 + q*8);
            C3 = __builtin_amdgcn_mfma_f32_16x16x32_bf16(A3, B3[s], C3, 0, 0, 0);
        }
        #pragma unroll
        for (int rg = 0; rg < 4; ++rg) {
            const int rowid = rowbase + q*4 + rg;
            float e = C3[rg];
            e = e > 0.f ? e : 0.f;
            acc[rg] += (rowid < NN-1) ? e : 0.f;
        }
    }

    float s = (acc[0] + acc[1]) + (acc[2] + acc[3]);
    s += __shfl_xor(s, 16, 64);
    s += __shfl_xor(s, 32, 64);
    if (lane < DE) red[wave][lane] = s;
    __syncthreads();
    if (wave == 0 && lane < DE) {
        float tot = red[0][lane] + red[1][lane] + red[2][lane] + red[3][lane];
        ebar[bi*DE + lane] = tot;
    }
}

// ---------------------------------------------------------------------------
// Object MLP (unchanged): [x(16)|Ebar(5)] -> 128 -> 64 -> 6 relu
// ---------------------------------------------------------------------------
__global__ __launch_bounds__(512)
void obj_mlp_kernel(const float* __restrict__ x, const float* __restrict__ ebar,
                    const float* __restrict__ w1, const float* __restrict__ b1,
                    const float* __restrict__ w2, const float* __restrict__ b2,
                    const float* __restrict__ w3, const float* __restrict__ b3,
                    float* __restrict__ o_out)
{
    __shared__ float sW[HID*HH2];
    __shared__ float sB1[HID];
    __shared__ float sB2[HH2];
    __shared__ float sCin[RT*KO];
    __shared__ float sH1[RT*HID];
    __shared__ float sH2t[HH2*(RT+1)];
    const int tid = threadIdx.x;
    const int rbase = blockIdx.x * RT;

    for (int i = tid; i < KO*HID; i += 512) sW[i] = w1[i];
    if (tid < HID) sB1[tid] = b1[tid];
    else if (tid < HID+HH2) sB2[tid-HID] = b2[tid-HID];
    for (int i = tid; i < RT*KO; i += 512) {
        int r = i / KO, k = i - r*KO;
        int gr = rbase + r;
        int b = gr / NN;
        int node = gr - b*NN;
        sCin[i] = (k < PP) ? x[(b*NN+node)*PP + k]
                           : ebar[(b*NN+node)*DE + (k-PP)];
    }
    __syncthreads();

    {
        const int j = tid & (HID-1);
        const int g = tid >> 7;
        float w[KO];
        #pragma unroll
        for (int k = 0; k < KO; ++k) w[k] = sW[k*HID + j];
        const float bj = sB1[j];
        #pragma unroll
        for (int rr = 0; rr < 8; ++rr) {
            const int r = g*8 + rr;
            const float* e = &sCin[r*KO];
            float a0=0.f,a1=0.f,a2=0.f;
            #pragma unroll
            for (int k = 0; k < KO; k += 3) {
                a0 += w[k+0]*e[k+0];
                a1 += w[k+1]*e[k+1];
                a2 += w[k+2]*e[k+2];
            }
            float v = a0+a1+a2+bj;
            sH1[r*HID + j] = v > 0.f ? v : 0.f;
        }
    }
    __syncthreads();
    for (int i = tid; i < HID*HH2; i += 512) sW[i] = w2[i];
    __syncthreads();

    {
        const int j = tid & (HH2-1);
        const int g = tid >> 6;
        float acc[4];
        #pragma unroll
        for (int rr = 0; rr < 4; ++rr) acc[rr] = sB2[j];
        #pragma unroll
        for (int kc = 0; kc < HID; kc += 32) {
            float w[32];
            #pragma unroll
            for (int kk = 0; kk < 32; ++kk) w[kk] = sW[(kc+kk)*HH2 + j];
            #pragma unroll
            for (int rr = 0; rr < 4; ++rr) {
                const float* h = &sH1[(g*4+rr)*HID + kc];
                float a0=0.f,a1=0.f,a2=0.f,a3=0.f;
                #pragma unroll
                for (int kk = 0; kk < 32; kk += 4) {
                    a0 += w[kk+0]*h[kk+0];
                    a1 += w[kk+1]*h[kk+1];
                    a2 += w[kk+2]*h[kk+2];
                    a3 += w[kk+3]*h[kk+3];
                }
                acc[rr] += (a0+a1)+(a2+a3);
            }
        }
        #pragma unroll
        for (int rr = 0; rr < 4; ++rr) {
            float v = acc[rr];
            sH2t[j*(RT+1) + (g*4+rr)] = v > 0.f ? v : 0.f;
        }
    }
    __syncthreads();

    if (tid < RT*DO) {
        const int r = tid & (RT-1);
        const int c = tid >> 5;
        float a0=0.f,a1=0.f,a2=0.f,a3=0.f;
        #pragma unroll
        for (int k = 0; k < HH2; k += 4) {
            a0 += sH2t[(k+0)*(RT+1)+r]*w3[(k+0)*DO+c];
            a1 += sH2t[(k+1)*(RT+1)+r]*w3[(k+1)*DO+c];
            a2 += sH2t[(k+2)*(RT+1)+r]*w3[(k+2)*DO+c];
            a3 += sH2t[(k+3)*(RT+1)+r]*w3[(k+3)*DO+c];
        }
        float v = (a0+a1)+(a2+a3) + b3[c];
        v = v > 0.f ? v : 0.f;
        int gr = rbase + r;
        int b = gr / NN;
        int node = gr - b*NN;
        o_out[b*(NN*DO) + node*DO + c] = v;
    }
}

// ---------------------------------------------------------------------------
// Classifier: 1128 -> 128 relu -> 64 relu -> 5. float4 LDS + 4 accumulators.
// ---------------------------------------------------------------------------
__global__ __launch_bounds__(256)
void fc_kernel(const float* __restrict__ o_in,
               const float* __restrict__ w1, const float* __restrict__ b1,
               const float* __restrict__ w2, const float* __restrict__ b2,
               const float* __restrict__ w3, const float* __restrict__ b3,
               float* __restrict__ out)
{
    __shared__ __align__(16) float s_in[NN*DO];   // 1128
    __shared__ float s_p[256];
    __shared__ float s_h1[HID];
    __shared__ float s_h2[HH2];
    const int b = blockIdx.x, tid = threadIdx.x;

    for (int i = tid; i < NN*DO; i += 256) s_in[i] = o_in[b*(NN*DO) + i];
    __syncthreads();

    {
        const int j = tid & (HID-1);
        const int h = tid >> 7;                 // 564 = 141 float4s per half
        const float4* s4 = (const float4*)&s_in[h*564];
        const float* wbase = w1 + (size_t)(h*564)*HID + j;
        float a0=0.f,a1=0.f,a2=0.f,a3=0.f;
        #pragma unroll 4
        for (int i = 0; i < 141; ++i) {
            float4 v = s4[i];
            const float* wp = wbase + (size_t)i*4*HID;
            a0 += v.x * wp[0];
            a1 += v.y * wp[HID];
            a2 += v.z * wp[2*HID];
            a3 += v.w * wp[3*HID];
        }
        s_p[tid] = (a0+a1)+(a2+a3);
    }
    __syncthreads();
    if (tid < HID) {
        float v = s_p[tid] + s_p[tid+HID] + b1[tid];
        s_h1[tid] = v > 0.f ? v : 0.f;
    }
    __syncthreads();

    {
        const int j = tid & (HH2-1);
        const int q = tid >> 6;
        float acc = 0.f;
        #pragma unroll
        for (int kk = 0; kk < 32; ++kk) {
            int k = q*32 + kk;
            acc += s_h1[k] * w2[k*HH2 + j];
        }
        s_p[tid] = acc;
    }
    __syncthreads();
    if (tid < HH2) {
        float v = s_p[tid] + s_p[tid+64] + s_p[tid+128] + s_p[tid+192] + b2[tid];
        s_h2[tid] = v > 0.f ? v : 0.f;
    }
    __syncthreads();

    if (tid < NT) {
        float acc = b3[tid];
        #pragma unroll
        for (int k = 0; k < HH2; ++k)
            acc += s_h2[k] * w3[k*NT + tid];
        out[b*NT + tid] = acc;
    }
}

extern "C" void kernel_launch(void* const* d_in, const int* in_sizes, int n_in,
                              void* d_out, int out_size, void* d_ws, size_t ws_size,
                              hipStream_t stream) {
    (void)in_sizes; (void)n_in; (void)out_size; (void)ws_size;
    const float* x     = (const float*)d_in[0];
    const float* fr1_w = (const float*)d_in[1];
    const float* fr1_b = (const float*)d_in[2];
    const float* fr2_w = (const float*)d_in[3];
    const float* fr2_b = (const float*)d_in[4];
    const float* fr3_w = (const float*)d_in[5];
    const float* fr3_b = (const float*)d_in[6];
    const float* fo1_w = (const float*)d_in[7];
    const float* fo1_b = (const float*)d_in[8];
    const float* fo2_w = (const float*)d_in[9];
    const float* fo2_b = (const float*)d_in[10];
    const float* fo3_w = (const float*)d_in[11];
    const float* fo3_b = (const float*)d_in[12];
    const float* fc1_w = (const float*)d_in[13];
    const float* fc1_b = (const float*)d_in[14];
    const float* fc2_w = (const float*)d_in[15];
    const float* fc2_b = (const float*)d_in[16];
    const float* fc3_w = (const float*)d_in[17];
    const float* fc3_b = (const float*)d_in[18];

    short* ws_s = (short*)d_ws;
    size_t fbase = ((size_t)SHORT_TOTAL*2 + 15) & ~(size_t)15;
    float* ebar = (float*)((char*)d_ws + fbase);            // [32][188][5]
    float* o_ws = ebar + BB*NN*DE;                          // [32][188][6]

    prep_kernel<<<128, 256, 0, stream>>>(x, fr1_w, fr2_w, fr3_w, ws_s);
    edge_mfma_kernel<<<BB*NN, 256, 0, stream>>>(ws_s, fr1_b, fr2_b, fr3_b, ebar);
    obj_mlp_kernel<<<ROWS_O/RT, 512, 0, stream>>>(
        x, ebar, fo1_w, fo1_b, fo2_w, fo2_b, fo3_w, fo3_b, o_ws);
    fc_kernel<<<BB, 256, 0, stream>>>(
        o_ws, fc1_w, fc1_b, fc2_w, fc2_b, fc3_w, fc3_b, (float*)d_out);
}

// Round 5
// 184.555 us; speedup vs baseline: 10.5505x; 1.0819x over previous
//
#include <hip/hip_runtime.h>

// GraphNet interaction network. Edge MLP via bf16 MFMA (fp32 accum).
// V4b: k-permuted W2/W3 so bf16 packing is lane-local; B2/B3 staged in
// block-shared LDS fragment-major. Fix vs V4: stage ALL 1152 uint4s (was 576).
#define BB   32
#define NN   188
#define PP   16
#define HID  128
#define HH2  64
#define DE   5
#define DO   6
#define NT   5
#define ROWS_O (BB*NN)
#define RT   32
#define KO   (PP+DE)

typedef __attribute__((ext_vector_type(8))) short short8;   // 8 bf16 = 4 VGPRs
typedef __attribute__((ext_vector_type(4))) float float4_;

__device__ __forceinline__ short f2bf(float v) {            // RNE (prep only)
    union { float f; unsigned u; } a; a.f = v;
    unsigned r = a.u + 0x7fff + ((a.u >> 16) & 1);
    return (short)(r >> 16);
}
// relu + round bits: hi16 of result is bf16(max(v,0)) (round-nearest)
__device__ __forceinline__ unsigned r2u(float v) {
    v = v > 0.f ? v : 0.f;
    return __float_as_uint(v) + 0x8000u;
}
// (hi16(hi)<<16) | hi16(lo)
__device__ __forceinline__ unsigned pack_hi16(unsigned hi, unsigned lo) {
    return __builtin_amdgcn_perm(hi, lo, 0x07060302);
}

// workspace layout (shorts)
#define XB_OFF    0                        // bf16 [32][188][24]
#define XB_ELTS   (BB*NN*24)               // 144384
#define W1T_OFF   (XB_OFF + XB_ELTS)       // bf16 [128 n][40 k]
#define W1T_ELTS  (HID*40)                 // 5120
#define W2S_OFF   (W1T_OFF + W1T_ELTS)     // swizzled frags [16][64 lanes][8]
#define W2S_ELTS  (16*64*8)                // 8192
#define W3S_OFF   (W2S_OFF + W2S_ELTS)     // swizzled frags [2][64][8]
#define W3S_ELTS  (2*64*8)                 // 1024
#define SHORT_TOTAL (W3S_OFF + W3S_ELTS)
#define WFRAG_UINT4 ((W2S_ELTS + W3S_ELTS) * 2 / 16)   // 1152

// pi-inverse for the k-pairing permutation (range 128 for W2, 64 for W3):
// pi(k): t=k>>4, n=k&15 -> (t>>1)*32 + n*2 + (t&1). Inverse:
__device__ __forceinline__ int pinv(int pk) {
    return ((pk >> 5) * 2 + (pk & 1)) * 16 + ((pk & 31) >> 1);
}

__global__ void prep_kernel(const float* __restrict__ x,
                            const float* __restrict__ w1,
                            const float* __restrict__ w2,
                            const float* __restrict__ w3,
                            short* __restrict__ ws)
{
    const int i = blockIdx.x * blockDim.x + threadIdx.x;
    const int stride = gridDim.x * blockDim.x;
    for (int idx = i; idx < BB*NN*PP; idx += stride) {       // x -> xb
        int row = idx >> 4, k = idx & 15;
        ws[XB_OFF + row*24 + k] = f2bf(x[idx]);
    }
    for (int idx = i; idx < 32*HID; idx += stride) {         // w1 [k][n] -> [n][40]
        int k = idx >> 7, n = idx & 127;
        ws[W1T_OFF + n*40 + k] = f2bf(w1[idx]);
    }
    for (int idx = i; idx < W2S_ELTS; idx += stride) {       // w2 -> swizzled frags
        int f = idx >> 9;            // frag = t*4+s
        int l = (idx >> 3) & 63;     // lane
        int e = idx & 7;
        int t = f >> 2, s = f & 3;
        int q = l >> 4, n16 = l & 15;
        int pk = s*32 + q*8 + e;
        int k = pinv(pk);
        int n = t*16 + n16;
        ws[W2S_OFF + idx] = f2bf(w2[k*HH2 + n]);
    }
    for (int idx = i; idx < W3S_ELTS; idx += stride) {       // w3 -> swizzled frags
        int s = idx >> 9;
        int l = (idx >> 3) & 63;
        int e = idx & 7;
        int q = l >> 4, n16 = l & 15;
        int pk = s*32 + q*8 + e;
        int k = pinv(pk);
        ws[W3S_OFF + idx] = (n16 < DE) ? f2bf(w3[k*DE + n16]) : (short)0;
    }
}

// ---------------------------------------------------------------------------
// Edge MLP: 32 -> 128 relu -> 64 relu -> 5 relu, summed over 187 edges of one
// (batch, receiver). 256 threads = 4 waves; 3 row-tiles of 16 per wave.
// ---------------------------------------------------------------------------
__global__ __launch_bounds__(256)
void edge_mfma_kernel(const short* __restrict__ ws_s,
                      const float* __restrict__ b1,
                      const float* __restrict__ b2,
                      const float* __restrict__ b3,
                      float* __restrict__ ebar)
{
    const short* xb  = ws_s + XB_OFF;
    const short* w1t = ws_s + W1T_OFF;

    __shared__ __align__(16) unsigned wsmem[4608];    // w2 frags [4096 dw] + w3 frags [512 dw]
    __shared__ __align__(16) unsigned h1d[4][16*68];  // per-wave [row][68 dw]
    __shared__ __align__(16) unsigned h2d[4][16*36];  // per-wave [row][36 dw]
    __shared__ float red[4][8];

    const int bi   = blockIdx.x;           // b*188 + recv
    const int b    = bi / NN;
    const int recv = bi - b*NN;
    const int tid  = threadIdx.x;
    const int wave = tid >> 6;
    const int lane = tid & 63;
    const int n16  = lane & 15;
    const int q    = lane >> 4;

    // stage swizzled W2|W3 frags into LDS: 18432 B = 1152 uint4
    {
        const uint4* src = (const uint4*)(ws_s + W2S_OFF);
        uint4* dst = (uint4*)wsmem;
        #pragma unroll
        for (int i = 0; i < 5; ++i) {
            int idx = tid + i*256;
            if (idx < WFRAG_UINT4) dst[idx] = src[idx];
        }
    }

    // per-wave stationary B1 fragments (global, L2-hot)
    short8 B1[8];
    #pragma unroll
    for (int t = 0; t < 8; ++t)
        B1[t] = *(const short8*)(w1t + (t*16 + n16)*40 + q*8);

    float bias1[8];
    #pragma unroll
    for (int t = 0; t < 8; ++t) bias1[t] = b1[t*16 + n16];
    float bias2[4];
    #pragma unroll
    for (int t = 0; t < 4; ++t) bias2[t] = b2[t*16 + n16];
    const float bias3 = (n16 < DE) ? b3[n16] : 0.f;

    __syncthreads();    // wsmem ready

    const short* w2l = (const short*)wsmem;           // frag f: [f*512 + lane*8]
    const short* w3l = (const short*)(wsmem + 4096);  // frag s: [s*512 + lane*8]
    short8 B3[2];
    #pragma unroll
    for (int s = 0; s < 2; ++s)
        B3[s] = *(const short8*)(w3l + s*512 + lane*8);

    const short* xrow = xb + b*(NN*24);
    unsigned* h1w = &h1d[wave][0];
    unsigned* h2w = &h2d[wave][0];
    const short* h1r = (const short*)h1w;
    const short* h2r = (const short*)h2w;

    float acc[4] = {0.f, 0.f, 0.f, 0.f};

    #pragma unroll
    for (int ti = 0; ti < 3; ++ti) {
        const int rowbase = (wave*3 + ti) * 16;
        // A frag: [x[recv] | x[send_r]]
        const int r = rowbase + n16;
        int send = r + (r >= recv ? 1 : 0);
        if (send > NN-1) send = NN-1;
        const int node = (q < 2) ? recv : send;
        const int koff = (q & 1) * 8;
        short8 A1 = *(const short8*)(xrow + node*24 + koff);

        // ---- layer 1: 8 N-tiles as 4 pairs; pack (t,t+1) lane-locally ----
        #pragma unroll
        for (int m = 0; m < 4; ++m) {
            float4_ Ca = (float4_){bias1[2*m],   bias1[2*m],   bias1[2*m],   bias1[2*m]};
            float4_ Cb = (float4_){bias1[2*m+1], bias1[2*m+1], bias1[2*m+1], bias1[2*m+1]};
            Ca = __builtin_amdgcn_mfma_f32_16x16x32_bf16(A1, B1[2*m],   Ca, 0, 0, 0);
            Cb = __builtin_amdgcn_mfma_f32_16x16x32_bf16(A1, B1[2*m+1], Cb, 0, 0, 0);
            #pragma unroll
            for (int rg = 0; rg < 4; ++rg)
                h1w[(q*4+rg)*68 + m*16 + n16] = pack_hi16(r2u(Cb[rg]), r2u(Ca[rg]));
        }

        // ---- layer 2: A from wave-private LDS; B frags from shared LDS ----
        short8 A2[4];
        #pragma unroll
        for (int s = 0; s < 4; ++s)
            A2[s] = *(const short8*)(h1r + n16*136 + s*32 + q*8);
        #pragma unroll
        for (int m = 0; m < 2; ++m) {
            float4_ Ca = (float4_){bias2[2*m],   bias2[2*m],   bias2[2*m],   bias2[2*m]};
            float4_ Cb = (float4_){bias2[2*m+1], bias2[2*m+1], bias2[2*m+1], bias2[2*m+1]};
            #pragma unroll
            for (int s = 0; s < 4; ++s) {
                short8 Ba = *(const short8*)(w2l + ((2*m)*4+s)*512 + lane*8);
                short8 Bb = *(const short8*)(w2l + ((2*m+1)*4+s)*512 + lane*8);
                Ca = __builtin_amdgcn_mfma_f32_16x16x32_bf16(A2[s], Ba, Ca, 0, 0, 0);
                Cb = __builtin_amdgcn_mfma_f32_16x16x32_bf16(A2[s], Bb, Cb, 0, 0, 0);
            }
            #pragma unroll
            for (int rg = 0; rg < 4; ++rg)
                h2w[(q*4+rg)*36 + m*16 + n16] = pack_hi16(r2u(Cb[rg]), r2u(Ca[rg]));
        }

        // ---- layer 3: N=16 (5 used), K=64 ----
        float4_ C3 = (float4_){bias3, bias3, bias3, bias3};
        #pragma unroll
        for (int s = 0; s < 2; ++s) {
            short8 A3 = *(const short8*)(h2r + n16*72 + s*32 + q*8);
            C3 = __builtin_amdgcn_mfma_f32_16x16x32_bf16(A3, B3[s], C3, 0, 0, 0);
        }
        #pragma unroll
        for (int rg = 0; rg < 4; ++rg) {
            const int rowid = rowbase + q*4 + rg;
            float e = C3[rg];
            e = e > 0.f ? e : 0.f;
            acc[rg] += (rowid < NN-1) ? e : 0.f;
        }
    }

    float s = (acc[0] + acc[1]) + (acc[2] + acc[3]);
    s += __shfl_xor(s, 16, 64);
    s += __shfl_xor(s, 32, 64);
    if (lane < DE) red[wave][lane] = s;
    __syncthreads();
    if (wave == 0 && lane < DE) {
        float tot = red[0][lane] + red[1][lane] + red[2][lane] + red[3][lane];
        ebar[bi*DE + lane] = tot;
    }
}

// ---------------------------------------------------------------------------
// Object MLP (unchanged): [x(16)|Ebar(5)] -> 128 -> 64 -> 6 relu
// ---------------------------------------------------------------------------
__global__ __launch_bounds__(512)
void obj_mlp_kernel(const float* __restrict__ x, const float* __restrict__ ebar,
                    const float* __restrict__ w1, const float* __restrict__ b1,
                    const float* __restrict__ w2, const float* __restrict__ b2,
                    const float* __restrict__ w3, const float* __restrict__ b3,
                    float* __restrict__ o_out)
{
    __shared__ float sW[HID*HH2];
    __shared__ float sB1[HID];
    __shared__ float sB2[HH2];
    __shared__ float sCin[RT*KO];
    __shared__ float sH1[RT*HID];
    __shared__ float sH2t[HH2*(RT+1)];
    const int tid = threadIdx.x;
    const int rbase = blockIdx.x * RT;

    for (int i = tid; i < KO*HID; i += 512) sW[i] = w1[i];
    if (tid < HID) sB1[tid] = b1[tid];
    else if (tid < HID+HH2) sB2[tid-HID] = b2[tid-HID];
    for (int i = tid; i < RT*KO; i += 512) {
        int r = i / KO, k = i - r*KO;
        int gr = rbase + r;
        int b = gr / NN;
        int node = gr - b*NN;
        sCin[i] = (k < PP) ? x[(b*NN+node)*PP + k]
                           : ebar[(b*NN+node)*DE + (k-PP)];
    }
    __syncthreads();

    {
        const int j = tid & (HID-1);
        const int g = tid >> 7;
        float w[KO];
        #pragma unroll
        for (int k = 0; k < KO; ++k) w[k] = sW[k*HID + j];
        const float bj = sB1[j];
        #pragma unroll
        for (int rr = 0; rr < 8; ++rr) {
            const int r = g*8 + rr;
            const float* e = &sCin[r*KO];
            float a0=0.f,a1=0.f,a2=0.f;
            #pragma unroll
            for (int k = 0; k < KO; k += 3) {
                a0 += w[k+0]*e[k+0];
                a1 += w[k+1]*e[k+1];
                a2 += w[k+2]*e[k+2];
            }
            float v = a0+a1+a2+bj;
            sH1[r*HID + j] = v > 0.f ? v : 0.f;
        }
    }
    __syncthreads();
    for (int i = tid; i < HID*HH2; i += 512) sW[i] = w2[i];
    __syncthreads();

    {
        const int j = tid & (HH2-1);
        const int g = tid >> 6;
        float acc[4];
        #pragma unroll
        for (int rr = 0; rr < 4; ++rr) acc[rr] = sB2[j];
        #pragma unroll
        for (int kc = 0; kc < HID; kc += 32) {
            float w[32];
            #pragma unroll
            for (int kk = 0; kk < 32; ++kk) w[kk] = sW[(kc+kk)*HH2 + j];
            #pragma unroll
            for (int rr = 0; rr < 4; ++rr) {
                const float* h = &sH1[(g*4+rr)*HID + kc];
                float a0=0.f,a1=0.f,a2=0.f,a3=0.f;
                #pragma unroll
                for (int kk = 0; kk < 32; kk += 4) {
                    a0 += w[kk+0]*h[kk+0];
                    a1 += w[kk+1]*h[kk+1];
                    a2 += w[kk+2]*h[kk+2];
                    a3 += w[kk+3]*h[kk+3];
                }
                acc[rr] += (a0+a1)+(a2+a3);
            }
        }
        #pragma unroll
        for (int rr = 0; rr < 4; ++rr) {
            float v = acc[rr];
            sH2t[j*(RT+1) + (g*4+rr)] = v > 0.f ? v : 0.f;
        }
    }
    __syncthreads();

    if (tid < RT*DO) {
        const int r = tid & (RT-1);
        const int c = tid >> 5;
        float a0=0.f,a1=0.f,a2=0.f,a3=0.f;
        #pragma unroll
        for (int k = 0; k < HH2; k += 4) {
            a0 += sH2t[(k+0)*(RT+1)+r]*w3[(k+0)*DO+c];
            a1 += sH2t[(k+1)*(RT+1)+r]*w3[(k+1)*DO+c];
            a2 += sH2t[(k+2)*(RT+1)+r]*w3[(k+2)*DO+c];
            a3 += sH2t[(k+3)*(RT+1)+r]*w3[(k+3)*DO+c];
        }
        float v = (a0+a1)+(a2+a3) + b3[c];
        v = v > 0.f ? v : 0.f;
        int gr = rbase + r;
        int b = gr / NN;
        int node = gr - b*NN;
        o_out[b*(NN*DO) + node*DO + c] = v;
    }
}

// ---------------------------------------------------------------------------
// Classifier (unchanged): 1128 -> 128 relu -> 64 relu -> 5
// ---------------------------------------------------------------------------
__global__ __launch_bounds__(256)
void fc_kernel(const float* __restrict__ o_in,
               const float* __restrict__ w1, const float* __restrict__ b1,
               const float* __restrict__ w2, const float* __restrict__ b2,
               const float* __restrict__ w3, const float* __restrict__ b3,
               float* __restrict__ out)
{
    __shared__ __align__(16) float s_in[NN*DO];
    __shared__ float s_p[256];
    __shared__ float s_h1[HID];
    __shared__ float s_h2[HH2];
    const int b = blockIdx.x, tid = threadIdx.x;

    for (int i = tid; i < NN*DO; i += 256) s_in[i] = o_in[b*(NN*DO) + i];
    __syncthreads();

    {
        const int j = tid & (HID-1);
        const int h = tid >> 7;
        const float4* s4 = (const float4*)&s_in[h*564];
        const float* wbase = w1 + (size_t)(h*564)*HID + j;
        float a0=0.f,a1=0.f,a2=0.f,a3=0.f;
        #pragma unroll 4
        for (int i = 0; i < 141; ++i) {
            float4 v = s4[i];
            const float* wp = wbase + (size_t)i*4*HID;
            a0 += v.x * wp[0];
            a1 += v.y * wp[HID];
            a2 += v.z * wp[2*HID];
            a3 += v.w * wp[3*HID];
        }
        s_p[tid] = (a0+a1)+(a2+a3);
    }
    __syncthreads();
    if (tid < HID) {
        float v = s_p[tid] + s_p[tid+HID] + b1[tid];
        s_h1[tid] = v > 0.f ? v : 0.f;
    }
    __syncthreads();

    {
        const int j = tid & (HH2-1);
        const int q = tid >> 6;
        float acc = 0.f;
        #pragma unroll
        for (int kk = 0; kk < 32; ++kk) {
            int k = q*32 + kk;
            acc += s_h1[k] * w2[k*HH2 + j];
        }
        s_p[tid] = acc;
    }
    __syncthreads();
    if (tid < HH2) {
        float v = s_p[tid] + s_p[tid+64] + s_p[tid+128] + s_p[tid+192] + b2[tid];
        s_h2[tid] = v > 0.f ? v : 0.f;
    }
    __syncthreads();

    if (tid < NT) {
        float acc = b3[tid];
        #pragma unroll
        for (int k = 0; k < HH2; ++k)
            acc += s_h2[k] * w3[k*NT + tid];
        out[b*NT + tid] = acc;
    }
}

extern "C" void kernel_launch(void* const* d_in, const int* in_sizes, int n_in,
                              void* d_out, int out_size, void* d_ws, size_t ws_size,
                              hipStream_t stream) {
    (void)in_sizes; (void)n_in; (void)out_size; (void)ws_size;
    const float* x     = (const float*)d_in[0];
    const float* fr1_w = (const float*)d_in[1];
    const float* fr1_b = (const float*)d_in[2];
    const float* fr2_w = (const float*)d_in[3];
    const float* fr2_b = (const float*)d_in[4];
    const float* fr3_w = (const float*)d_in[5];
    const float* fr3_b = (const float*)d_in[6];
    const float* fo1_w = (const float*)d_in[7];
    const float* fo1_b = (const float*)d_in[8];
    const float* fo2_w = (const float*)d_in[9];
    const float* fo2_b = (const float*)d_in[10];
    const float* fo3_w = (const float*)d_in[11];
    const float* fo3_b = (const float*)d_in[12];
    const float* fc1_w = (const float*)d_in[13];
    const float* fc1_b = (const float*)d_in[14];
    const float* fc2_w = (const float*)d_in[15];
    const float* fc2_b = (const float*)d_in[16];
    const float* fc3_w = (const float*)d_in[17];
    const float* fc3_b = (const float*)d_in[18];

    short* ws_s = (short*)d_ws;
    size_t fbase = ((size_t)SHORT_TOTAL*2 + 15) & ~(size_t)15;
    float* ebar = (float*)((char*)d_ws + fbase);            // [32][188][5]
    float* o_ws = ebar + BB*NN*DE;                          // [32][188][6]

    prep_kernel<<<128, 256, 0, stream>>>(x, fr1_w, fr2_w, fr3_w, ws_s);
    edge_mfma_kernel<<<BB*NN, 256, 0, stream>>>(ws_s, fr1_b, fr2_b, fr3_b, ebar);
    obj_mlp_kernel<<<ROWS_O/RT, 512, 0, stream>>>(
        x, ebar, fo1_w, fo1_b, fo2_w, fo2_b, fo3_w, fo3_b, o_ws);
    fc_kernel<<<BB, 256, 0, stream>>>(
        o_ws, fc1_w, fc1_b, fc2_w, fc2_b, fc3_w, fc3_b, (float*)d_out);
}